// Round 2
// baseline (4485.732 us; speedup 1.0000x reference)
//
#include <hip/hip_runtime.h>
#include <hip/hip_bf16.h>

// Problem constants
#define D_MODEL 1024
#define D_INNER 4096
#define D_STATE 16
#define D_CONV 4
#define DT_RANK 64
#define BATCH 2
#define SEQLEN 2048
#define MROWS (BATCH * SEQLEN)          // 4096
#define NPROJ (DT_RANK + 2 * D_STATE)   // 96

typedef unsigned short u16;
typedef unsigned int u32;

__device__ __forceinline__ float bf2f(u16 u) {
    union { u32 i; float f; } v; v.i = ((u32)u) << 16; return v.f;
}
__device__ __forceinline__ u16 f2bf(float f) {
    union { float f; u32 i; } v; v.f = f;
    u32 x = v.i;
    u32 r = x + 0x7fffu + ((x >> 16) & 1u);   // round to nearest even
    return (u16)(r >> 16);
}
__device__ __forceinline__ float softplusf(float x) {
    return x > 0.f ? x + log1pf(expf(-x)) : log1pf(expf(x));
}

// ---------------------------------------------------------------------------
// D0: detect input dtype. bf16 data: even-halfword exponents are sane (~100%).
// fp32 data: even halfwords are mantissa bits -> exponent field ~uniform (~16% sane).
__global__ __launch_bounds__(256) void detect_dtype(const u16* __restrict__ x, int* __restrict__ flag) {
    __shared__ int cnt;
    if (threadIdx.x == 0) cnt = 0;
    __syncthreads();
    int local = 0;
    for (int k = 0; k < 16; k++) {
        int e = threadIdx.x * 8192 + k * 512;      // element index < 2097152
        u16 v = x[2 * e];                          // u16 idx < 4193281, safe for bf16 buffer
        int ex = (v >> 7) & 0xFF;
        if (ex >= 0x68 && ex <= 0x8F) local++;     // |val| in [2^-23, 2^17]
    }
    atomicAdd(&cnt, local);
    __syncthreads();
    if (threadIdx.x == 0) *flag = (cnt >= 2458) ? 1 : 0;   // >=60% sane -> bf16
}

// ---------------------------------------------------------------------------
// Ingest a small input to canonical bf16
__global__ __launch_bounds__(256) void ingest16(const void* __restrict__ src, u16* __restrict__ dst,
                                                int n, const int* __restrict__ flag) {
    int i = blockIdx.x * 256 + threadIdx.x;
    if (i >= n) return;
    if (*flag) dst[i] = ((const u16*)src)[i];
    else       dst[i] = f2bf(((const float*)src)[i]);
}

// ---------------------------------------------------------------------------
// P: A = -exp(A_log)  [D_INNER * D_STATE], dual-dtype read
__global__ __launch_bounds__(256) void prep_A(const void* __restrict__ A_log, float* __restrict__ A,
                                              const int* __restrict__ flag) {
    int i = blockIdx.x * 256 + threadIdx.x;
    if (i >= D_INNER * D_STATE) return;
    float v = (*flag) ? bf2f(((const u16*)A_log)[i]) : ((const float*)A_log)[i];
    A[i] = -expf(v);
}

// ---------------------------------------------------------------------------
// K1: one half of xz = x @ in_proj_w.  col0 selects xc (0) or z (4096) half.
// Output stored bf16 into dst[4096 x 4096].
__global__ __launch_bounds__(256) void gemm_in(const void* __restrict__ xv, const void* __restrict__ Wv,
                                               u16* __restrict__ dst, int col0, const int* __restrict__ flag) {
    const int K = D_MODEL, NB = 2 * D_INNER;
    __shared__ float As[16][65];
    __shared__ float Bs[16][64];
    int isb = *flag;
    int tid = threadIdx.x;
    int m0 = blockIdx.y * 64, n0 = blockIdx.x * 64;
    int tx = tid & 15, ty = tid >> 4;
    float acc[4][4] = {};
    for (int k0 = 0; k0 < K; k0 += 16) {
        {   // A tile: 64 rows x 16 k
            int l = tid * 4;
            int row = l >> 4, kk = l & 15;
            size_t ai = (size_t)(m0 + row) * K + k0 + kk;
            float a0, a1, a2, a3;
            if (isb) { ushort4 av = *(const ushort4*)((const u16*)xv + ai);
                       a0 = bf2f(av.x); a1 = bf2f(av.y); a2 = bf2f(av.z); a3 = bf2f(av.w); }
            else     { float4 af = *(const float4*)((const float*)xv + ai);
                       a0 = af.x; a1 = af.y; a2 = af.z; a3 = af.w; }
            As[kk + 0][row] = a0; As[kk + 1][row] = a1;
            As[kk + 2][row] = a2; As[kk + 3][row] = a3;
        }
        {   // B tile: 16 k x 64 n
            int l = tid * 4;
            int r = l >> 6, c = l & 63;
            size_t bi = (size_t)(k0 + r) * NB + col0 + n0 + c;
            float4 bf4;
            if (isb) { ushort4 bv = *(const ushort4*)((const u16*)Wv + bi);
                       bf4 = make_float4(bf2f(bv.x), bf2f(bv.y), bf2f(bv.z), bf2f(bv.w)); }
            else     { bf4 = *(const float4*)((const float*)Wv + bi); }
            *(float4*)&Bs[r][c] = bf4;
        }
        __syncthreads();
#pragma unroll
        for (int kk = 0; kk < 16; kk++) {
            float a0 = As[kk][ty * 4 + 0], a1 = As[kk][ty * 4 + 1];
            float a2 = As[kk][ty * 4 + 2], a3 = As[kk][ty * 4 + 3];
            float4 b4 = *(float4*)&Bs[kk][tx * 4];
            acc[0][0] += a0 * b4.x; acc[0][1] += a0 * b4.y; acc[0][2] += a0 * b4.z; acc[0][3] += a0 * b4.w;
            acc[1][0] += a1 * b4.x; acc[1][1] += a1 * b4.y; acc[1][2] += a1 * b4.z; acc[1][3] += a1 * b4.w;
            acc[2][0] += a2 * b4.x; acc[2][1] += a2 * b4.y; acc[2][2] += a2 * b4.z; acc[2][3] += a2 * b4.w;
            acc[3][0] += a3 * b4.x; acc[3][1] += a3 * b4.y; acc[3][2] += a3 * b4.z; acc[3][3] += a3 * b4.w;
        }
        __syncthreads();
    }
#pragma unroll
    for (int i = 0; i < 4; i++) {
        int mm = m0 + ty * 4 + i;
#pragma unroll
        for (int j = 0; j < 4; j++) {
            int nn = n0 + tx * 4 + j;
            dst[(size_t)mm * D_INNER + nn] = f2bf(acc[i][j]);
        }
    }
}

// ---------------------------------------------------------------------------
// K2: causal depthwise conv1d + silu (bf16 in/out)
__global__ __launch_bounds__(256) void conv_silu(const u16* __restrict__ xc, const u16* __restrict__ cw,
                                                 const u16* __restrict__ cb, u16* __restrict__ xs) {
    int idx = blockIdx.x * 256 + threadIdx.x;   // b*2048*4096 + t*4096 + d
    int d = idx & (D_INNER - 1);
    int t = (idx >> 12) & (SEQLEN - 1);
    int b = idx >> 23;
    float w0 = bf2f(cw[d * 4 + 0]), w1 = bf2f(cw[d * 4 + 1]);
    float w2 = bf2f(cw[d * 4 + 2]), w3 = bf2f(cw[d * 4 + 3]);
    float acc = bf2f(cb[d]);
    size_t base = (size_t)b * SEQLEN * D_INNER + d;
    if (t >= 3) acc += bf2f(xc[base + (size_t)(t - 3) * D_INNER]) * w0;
    if (t >= 2) acc += bf2f(xc[base + (size_t)(t - 2) * D_INNER]) * w1;
    if (t >= 1) acc += bf2f(xc[base + (size_t)(t - 1) * D_INNER]) * w2;
    acc += bf2f(xc[base + (size_t)t * D_INNER]) * w3;
    float s = acc / (1.f + expf(-acc));
    xs[idx] = f2bf(s);
}

// ---------------------------------------------------------------------------
// K3: proj = xs @ x_proj_w   [4096,4096] x [4096,96] -> fp32
__global__ __launch_bounds__(128) void proj_gemm(const u16* __restrict__ xs, const u16* __restrict__ W,
                                                 float* __restrict__ proj) {
    __shared__ float xt[8][64];
    int m0 = blockIdx.x * 8;
    int tid = threadIdx.x;
    int j = tid;   // active for j < 96
    float acc[8] = {};
    for (int k0 = 0; k0 < D_INNER; k0 += 64) {
        int l = tid * 4;
        int r = l >> 6, c = l & 63;
        ushort4 v = *(const ushort4*)(&xs[(size_t)(m0 + r) * D_INNER + k0 + c]);
        xt[r][c + 0] = bf2f(v.x); xt[r][c + 1] = bf2f(v.y);
        xt[r][c + 2] = bf2f(v.z); xt[r][c + 3] = bf2f(v.w);
        __syncthreads();
        if (j < NPROJ) {
            for (int kk = 0; kk < 64; kk++) {
                float w = bf2f(W[(size_t)(k0 + kk) * NPROJ + j]);
#pragma unroll
                for (int r2 = 0; r2 < 8; r2++) acc[r2] += xt[r2][kk] * w;
            }
        }
        __syncthreads();
    }
    if (j < NPROJ) {
#pragma unroll
        for (int r2 = 0; r2 < 8; r2++) proj[(size_t)(m0 + r2) * NPROJ + j] = acc[r2];
    }
}

// ---------------------------------------------------------------------------
// K4: fused SSM scan: on-the-fly dt = softplus(proj_lo . dtW_col + b),
// recurrence, y reduction, gating; writes gated y (bf16) over xs.
// One lane per (b,d,n); block = 16 (b,d) groups; proj row double-buffered in LDS.
__global__ __launch_bounds__(256) void ssm_scan(const float* __restrict__ proj, const float* __restrict__ A,
                                                const u16* __restrict__ dtw16, const u16* __restrict__ dtb16,
                                                const u16* __restrict__ D16, const u16* __restrict__ z16,
                                                u16* __restrict__ xs16) {
    __shared__ float pl[2][96];
    int tid = threadIdx.x;
    int n = tid & 15;
    int g = blockIdx.x * 16 + (tid >> 4);
    int d = g & (D_INNER - 1);
    int b = g >> 12;
    float An = A[d * D_STATE + n];
    float Dd = bf2f(D16[d]);
    float btd = bf2f(dtb16[d]);
    float w0 = bf2f(dtw16[(size_t)(4 * n + 0) * D_INNER + d]);
    float w1 = bf2f(dtw16[(size_t)(4 * n + 1) * D_INNER + d]);
    float w2 = bf2f(dtw16[(size_t)(4 * n + 2) * D_INNER + d]);
    float w3 = bf2f(dtw16[(size_t)(4 * n + 3) * D_INNER + d]);
    const float* prow = proj + (size_t)b * SEQLEN * NPROJ;
    size_t base = (size_t)b * SEQLEN * D_INNER + d;
    if (tid < NPROJ) pl[0][tid] = prow[tid];
    __syncthreads();
    float h = 0.f;
    for (int t = 0; t < SEQLEN; t++) {
        int cur = t & 1;
        float pre = 0.f;
        if (tid < NPROJ && t + 1 < SEQLEN) pre = prow[(size_t)(t + 1) * NPROJ + tid];
        float p0 = pl[cur][4 * n + 0], p1 = pl[cur][4 * n + 1];
        float p2 = pl[cur][4 * n + 2], p3 = pl[cur][4 * n + 3];
        float Bv = pl[cur][DT_RANK + n], Cv = pl[cur][DT_RANK + D_STATE + n];
        float part = w0 * p0 + w1 * p1 + w2 * p2 + w3 * p3;
        part += __shfl_xor(part, 1, 16);
        part += __shfl_xor(part, 2, 16);
        part += __shfl_xor(part, 4, 16);
        part += __shfl_xor(part, 8, 16);
        float dt = softplusf(part + btd);
        size_t idx = base + (size_t)t * D_INNER;
        float u = bf2f(xs16[idx]);
        h = h * expf(dt * An) + dt * u * Bv;
        float p = h * Cv;
        p += __shfl_xor(p, 1, 16);
        p += __shfl_xor(p, 2, 16);
        p += __shfl_xor(p, 4, 16);
        p += __shfl_xor(p, 8, 16);
        if (n == 0) {
            float zv = bf2f(z16[idx]);
            float gate = zv / (1.f + expf(-zv));
            xs16[idx] = f2bf((p + u * Dd) * gate);
        }
        if (tid < NPROJ && t + 1 < SEQLEN) pl[1 - cur][tid] = pre;
        __syncthreads();
    }
}

// ---------------------------------------------------------------------------
// K5: out = y @ out_proj_w   A: bf16 [4096,4096]  B: dual [4096,1024] -> dual out
__global__ __launch_bounds__(256) void gemm_out(const u16* __restrict__ Y, const void* __restrict__ Wv,
                                                void* __restrict__ out, const int* __restrict__ flag) {
    const int K = D_INNER, N = D_MODEL;
    __shared__ float As[16][65];
    __shared__ float Bs[16][64];
    int isb = *flag;
    int tid = threadIdx.x;
    int m0 = blockIdx.y * 64, n0 = blockIdx.x * 64;
    int tx = tid & 15, ty = tid >> 4;
    float acc[4][4] = {};
    for (int k0 = 0; k0 < K; k0 += 16) {
        {
            int l = tid * 4;
            int row = l >> 4, kk = l & 15;
            ushort4 av = *(const ushort4*)(&Y[(size_t)(m0 + row) * K + k0 + kk]);
            As[kk + 0][row] = bf2f(av.x);
            As[kk + 1][row] = bf2f(av.y);
            As[kk + 2][row] = bf2f(av.z);
            As[kk + 3][row] = bf2f(av.w);
        }
        {
            int l = tid * 4;
            int r = l >> 6, c = l & 63;
            size_t bi = (size_t)(k0 + r) * N + n0 + c;
            float4 bf4;
            if (isb) { ushort4 bv = *(const ushort4*)((const u16*)Wv + bi);
                       bf4 = make_float4(bf2f(bv.x), bf2f(bv.y), bf2f(bv.z), bf2f(bv.w)); }
            else     { bf4 = *(const float4*)((const float*)Wv + bi); }
            *(float4*)&Bs[r][c] = bf4;
        }
        __syncthreads();
#pragma unroll
        for (int kk = 0; kk < 16; kk++) {
            float a0 = As[kk][ty * 4 + 0], a1 = As[kk][ty * 4 + 1];
            float a2 = As[kk][ty * 4 + 2], a3 = As[kk][ty * 4 + 3];
            float4 b4 = *(float4*)&Bs[kk][tx * 4];
            acc[0][0] += a0 * b4.x; acc[0][1] += a0 * b4.y; acc[0][2] += a0 * b4.z; acc[0][3] += a0 * b4.w;
            acc[1][0] += a1 * b4.x; acc[1][1] += a1 * b4.y; acc[1][2] += a1 * b4.z; acc[1][3] += a1 * b4.w;
            acc[2][0] += a2 * b4.x; acc[2][1] += a2 * b4.y; acc[2][2] += a2 * b4.z; acc[2][3] += a2 * b4.w;
            acc[3][0] += a3 * b4.x; acc[3][1] += a3 * b4.y; acc[3][2] += a3 * b4.z; acc[3][3] += a3 * b4.w;
        }
        __syncthreads();
    }
#pragma unroll
    for (int i = 0; i < 4; i++) {
        int mm = m0 + ty * 4 + i;
#pragma unroll
        for (int j = 0; j < 4; j++) {
            int nn = n0 + tx * 4 + j;
            if (isb) ((u16*)out)[(size_t)mm * N + nn] = f2bf(acc[i][j]);
            else     ((float*)out)[(size_t)mm * N + nn] = acc[i][j];
        }
    }
}

// ---------------------------------------------------------------------------
extern "C" void kernel_launch(void* const* d_in, const int* in_sizes, int n_in,
                              void* d_out, int out_size, void* d_ws, size_t ws_size,
                              hipStream_t stream) {
    const void* x          = d_in[0];
    const void* in_proj_w  = d_in[1];
    const void* conv_w     = d_in[2];
    const void* conv_b     = d_in[3];
    const void* x_proj_w   = d_in[4];
    const void* dt_proj_w  = d_in[5];
    const void* dt_proj_b  = d_in[6];
    const void* A_log      = d_in[7];
    const void* Dvec       = d_in[8];
    const void* out_proj_w = d_in[9];

    char* w = (char*)d_ws;
    const size_t MB = 1024 * 1024;
    int*   flag  = (int*)(w + 0);
    float* Aws   = (float*)(w + 1024);           // 256 KiB
    float* proj  = (float*)(w + 1 * MB);         // 1.5 MiB
    u16*   cw16  = (u16*)(w + 3 * MB);           // 32 KiB
    u16*   cb16  = (u16*)(w + 3 * MB + 64 * 1024);
    u16*   xpw16 = (u16*)(w + 3 * MB + 128 * 1024); // 768 KiB
    u16*   dtw16 = (u16*)(w + 4 * MB);           // 512 KiB
    u16*   dtb16 = (u16*)(w + 4 * MB + 600 * 1024);
    u16*   D16   = (u16*)(w + 4 * MB + 700 * 1024);
    u16*   buf1  = (u16*)(w + 5 * MB);           // 32 MiB : xc then z
    u16*   xs    = (u16*)(w + 37 * MB);          // 32 MiB : xs then gated y
    // total 69 MiB

    // D0: dtype flag
    detect_dtype<<<dim3(1), dim3(256), 0, stream>>>((const u16*)x, flag);

    // ingest small weights to canonical bf16
    ingest16<<<dim3(64), dim3(256), 0, stream>>>(conv_w, cw16, D_INNER * D_CONV, flag);
    ingest16<<<dim3(16), dim3(256), 0, stream>>>(conv_b, cb16, D_INNER, flag);
    ingest16<<<dim3(1536), dim3(256), 0, stream>>>(x_proj_w, xpw16, D_INNER * NPROJ, flag);
    ingest16<<<dim3(1024), dim3(256), 0, stream>>>(dt_proj_w, dtw16, DT_RANK * D_INNER, flag);
    ingest16<<<dim3(16), dim3(256), 0, stream>>>(dt_proj_b, dtb16, D_INNER, flag);
    ingest16<<<dim3(16), dim3(256), 0, stream>>>(Dvec, D16, D_INNER, flag);
    prep_A<<<dim3(256), dim3(256), 0, stream>>>(A_log, Aws, flag);

    // K1a: xc half
    gemm_in<<<dim3(64, 64), dim3(256), 0, stream>>>(x, in_proj_w, buf1, 0, flag);
    // K2: conv + silu -> xs
    conv_silu<<<dim3(MROWS * D_INNER / 256), dim3(256), 0, stream>>>(buf1, cw16, cb16, xs);
    // K3: proj
    proj_gemm<<<dim3(MROWS / 8), dim3(128), 0, stream>>>(xs, xpw16, proj);
    // K1b: z half (overwrites xc, which is dead now)
    gemm_in<<<dim3(64, 64), dim3(256), 0, stream>>>(x, in_proj_w, buf1, D_INNER, flag);
    // K4: fused scan (dt on the fly), writes gated y over xs
    ssm_scan<<<dim3(MROWS * D_INNER / (256 * SEQLEN) * (SEQLEN / 4) / 2 == 0 ? 512 : 512), dim3(256), 0, stream>>>(
        proj, Aws, dtw16, dtb16, D16, buf1, xs);
    // K5: out
    gemm_out<<<dim3(D_MODEL / 64, MROWS / 64), dim3(256), 0, stream>>>(xs, out_proj_w, d_out, flag);
}

// Round 3
// 2149.518 us; speedup vs baseline: 2.0869x; 2.0869x over previous
//
#include <hip/hip_runtime.h>
#include <hip/hip_bf16.h>

// Problem constants
#define D_MODEL 1024
#define D_INNER 4096
#define D_STATE 16
#define D_CONV 4
#define DT_RANK 64
#define BATCH 2
#define SEQLEN 2048
#define MROWS (BATCH * SEQLEN)          // 4096
#define NPROJ (DT_RANK + 2 * D_STATE)   // 96
#define NC 32                           // scan chunks
#define TC (SEQLEN / NC)                // 64 steps per chunk

typedef unsigned short u16;
typedef unsigned int u32;

__device__ __forceinline__ float bf2f(u16 u) {
    union { u32 i; float f; } v; v.i = ((u32)u) << 16; return v.f;
}
__device__ __forceinline__ u16 f2bf(float f) {
    union { float f; u32 i; } v; v.f = f;
    u32 x = v.i;
    u32 r = x + 0x7fffu + ((x >> 16) & 1u);   // round to nearest even
    return (u16)(r >> 16);
}
__device__ __forceinline__ float softplusf(float x) {
    return x > 0.f ? x + log1pf(expf(-x)) : log1pf(expf(x));
}

// ---------------------------------------------------------------------------
// D0: detect input dtype. bf16 data: even-halfword exponents are sane (~100%).
// fp32 data: even halfwords are mantissa bits -> exponent field ~uniform (~16% sane).
__global__ __launch_bounds__(256) void detect_dtype(const u16* __restrict__ x, int* __restrict__ flag) {
    __shared__ int cnt;
    if (threadIdx.x == 0) cnt = 0;
    __syncthreads();
    int local = 0;
    for (int k = 0; k < 16; k++) {
        int e = threadIdx.x * 8192 + k * 512;      // element index < 2097152
        u16 v = x[2 * e];                          // u16 idx < 4193281, safe for bf16 buffer
        int ex = (v >> 7) & 0xFF;
        if (ex >= 0x68 && ex <= 0x8F) local++;     // |val| in [2^-23, 2^17]
    }
    atomicAdd(&cnt, local);
    __syncthreads();
    if (threadIdx.x == 0) *flag = (cnt >= 2458) ? 1 : 0;   // >=60% sane -> bf16
}

// ---------------------------------------------------------------------------
__global__ __launch_bounds__(256) void ingest16(const void* __restrict__ src, u16* __restrict__ dst,
                                                int n, const int* __restrict__ flag) {
    int i = blockIdx.x * 256 + threadIdx.x;
    if (i >= n) return;
    if (*flag) dst[i] = ((const u16*)src)[i];
    else       dst[i] = f2bf(((const float*)src)[i]);
}

// ---------------------------------------------------------------------------
__global__ __launch_bounds__(256) void prep_A(const void* __restrict__ A_log, float* __restrict__ A,
                                              const int* __restrict__ flag) {
    int i = blockIdx.x * 256 + threadIdx.x;
    if (i >= D_INNER * D_STATE) return;
    float v = (*flag) ? bf2f(((const u16*)A_log)[i]) : ((const float*)A_log)[i];
    A[i] = -expf(v);
}

// ---------------------------------------------------------------------------
// K1: one half of xz = x @ in_proj_w.  col0 selects xc (0) or z (4096) half.
__global__ __launch_bounds__(256) void gemm_in(const void* __restrict__ xv, const void* __restrict__ Wv,
                                               u16* __restrict__ dst, int col0, const int* __restrict__ flag) {
    const int K = D_MODEL, NB = 2 * D_INNER;
    __shared__ float As[16][65];
    __shared__ float Bs[16][64];
    int isb = *flag;
    int tid = threadIdx.x;
    int m0 = blockIdx.y * 64, n0 = blockIdx.x * 64;
    int tx = tid & 15, ty = tid >> 4;
    float acc[4][4] = {};
    for (int k0 = 0; k0 < K; k0 += 16) {
        {
            int l = tid * 4;
            int row = l >> 4, kk = l & 15;
            size_t ai = (size_t)(m0 + row) * K + k0 + kk;
            float a0, a1, a2, a3;
            if (isb) { ushort4 av = *(const ushort4*)((const u16*)xv + ai);
                       a0 = bf2f(av.x); a1 = bf2f(av.y); a2 = bf2f(av.z); a3 = bf2f(av.w); }
            else     { float4 af = *(const float4*)((const float*)xv + ai);
                       a0 = af.x; a1 = af.y; a2 = af.z; a3 = af.w; }
            As[kk + 0][row] = a0; As[kk + 1][row] = a1;
            As[kk + 2][row] = a2; As[kk + 3][row] = a3;
        }
        {
            int l = tid * 4;
            int r = l >> 6, c = l & 63;
            size_t bi = (size_t)(k0 + r) * NB + col0 + n0 + c;
            float4 bf4;
            if (isb) { ushort4 bv = *(const ushort4*)((const u16*)Wv + bi);
                       bf4 = make_float4(bf2f(bv.x), bf2f(bv.y), bf2f(bv.z), bf2f(bv.w)); }
            else     { bf4 = *(const float4*)((const float*)Wv + bi); }
            *(float4*)&Bs[r][c] = bf4;
        }
        __syncthreads();
#pragma unroll
        for (int kk = 0; kk < 16; kk++) {
            float a0 = As[kk][ty * 4 + 0], a1 = As[kk][ty * 4 + 1];
            float a2 = As[kk][ty * 4 + 2], a3 = As[kk][ty * 4 + 3];
            float4 b4 = *(float4*)&Bs[kk][tx * 4];
            acc[0][0] += a0 * b4.x; acc[0][1] += a0 * b4.y; acc[0][2] += a0 * b4.z; acc[0][3] += a0 * b4.w;
            acc[1][0] += a1 * b4.x; acc[1][1] += a1 * b4.y; acc[1][2] += a1 * b4.z; acc[1][3] += a1 * b4.w;
            acc[2][0] += a2 * b4.x; acc[2][1] += a2 * b4.y; acc[2][2] += a2 * b4.z; acc[2][3] += a2 * b4.w;
            acc[3][0] += a3 * b4.x; acc[3][1] += a3 * b4.y; acc[3][2] += a3 * b4.z; acc[3][3] += a3 * b4.w;
        }
        __syncthreads();
    }
#pragma unroll
    for (int i = 0; i < 4; i++) {
        int mm = m0 + ty * 4 + i;
#pragma unroll
        for (int j = 0; j < 4; j++) {
            int nn = n0 + tx * 4 + j;
            dst[(size_t)mm * D_INNER + nn] = f2bf(acc[i][j]);
        }
    }
}

// ---------------------------------------------------------------------------
// K2: causal depthwise conv1d + silu (bf16 in/out)
__global__ __launch_bounds__(256) void conv_silu(const u16* __restrict__ xc, const u16* __restrict__ cw,
                                                 const u16* __restrict__ cb, u16* __restrict__ xs) {
    int idx = blockIdx.x * 256 + threadIdx.x;
    int d = idx & (D_INNER - 1);
    int t = (idx >> 12) & (SEQLEN - 1);
    int b = idx >> 23;
    float w0 = bf2f(cw[d * 4 + 0]), w1 = bf2f(cw[d * 4 + 1]);
    float w2 = bf2f(cw[d * 4 + 2]), w3 = bf2f(cw[d * 4 + 3]);
    float acc = bf2f(cb[d]);
    size_t base = (size_t)b * SEQLEN * D_INNER + d;
    if (t >= 3) acc += bf2f(xc[base + (size_t)(t - 3) * D_INNER]) * w0;
    if (t >= 2) acc += bf2f(xc[base + (size_t)(t - 2) * D_INNER]) * w1;
    if (t >= 1) acc += bf2f(xc[base + (size_t)(t - 1) * D_INNER]) * w2;
    acc += bf2f(xc[base + (size_t)t * D_INNER]) * w3;
    float s = acc / (1.f + expf(-acc));
    xs[idx] = f2bf(s);
}

// ---------------------------------------------------------------------------
// K3: proj = xs @ x_proj_w   [4096,4096] x [4096,96] -> fp32
__global__ __launch_bounds__(128) void proj_gemm(const u16* __restrict__ xs, const u16* __restrict__ W,
                                                 float* __restrict__ proj) {
    __shared__ float xt[8][64];
    int m0 = blockIdx.x * 8;
    int tid = threadIdx.x;
    int j = tid;
    float acc[8] = {};
    for (int k0 = 0; k0 < D_INNER; k0 += 64) {
        int l = tid * 4;
        int r = l >> 6, c = l & 63;
        ushort4 v = *(const ushort4*)(&xs[(size_t)(m0 + r) * D_INNER + k0 + c]);
        xt[r][c + 0] = bf2f(v.x); xt[r][c + 1] = bf2f(v.y);
        xt[r][c + 2] = bf2f(v.z); xt[r][c + 3] = bf2f(v.w);
        __syncthreads();
        if (j < NPROJ) {
            for (int kk = 0; kk < 64; kk++) {
                float w = bf2f(W[(size_t)(k0 + kk) * NPROJ + j]);
#pragma unroll
                for (int r2 = 0; r2 < 8; r2++) acc[r2] += xt[r2][kk] * w;
            }
        }
        __syncthreads();
    }
    if (j < NPROJ) {
#pragma unroll
        for (int r2 = 0; r2 < 8; r2++) proj[(size_t)(m0 + r2) * NPROJ + j] = acc[r2];
    }
}

// ---------------------------------------------------------------------------
// K4: dt = softplus(proj[:, :64] @ dt_proj_w + dt_proj_b) -> fp32 [B*T, D]
__global__ __launch_bounds__(256) void dt_gemm(const float* __restrict__ proj, const u16* __restrict__ dtW,
                                               const u16* __restrict__ dtb, float* __restrict__ dt) {
    __shared__ float pl[16][64];
    int d = blockIdx.x * 256 + threadIdx.x;
    int m0 = blockIdx.y * 16;
    {
        int l = threadIdx.x * 4;         // 1024 = 16*64
        int r = l >> 6, c = l & 63;
        float4 v = *(const float4*)(&proj[(size_t)(m0 + r) * NPROJ + c]);
        *(float4*)&pl[r][c] = v;
    }
    __syncthreads();
    float acc[16] = {};
    for (int r2 = 0; r2 < 64; r2++) {
        float w = bf2f(dtW[(size_t)r2 * D_INNER + d]);
#pragma unroll
        for (int i = 0; i < 16; i++) acc[i] += pl[i][r2] * w;
    }
    float b = bf2f(dtb[d]);
#pragma unroll
    for (int i = 0; i < 16; i++) {
        dt[(size_t)(m0 + i) * D_INNER + d] = softplusf(acc[i] + b);
    }
}

// ---------------------------------------------------------------------------
// K5a: chunked scan phase 1 — per (b,d,chunk) thread, 16 states in registers.
// Stores chunk-final state hloc[b][c][d][16] and S = sum(dt) over chunk.
__global__ __launch_bounds__(256) void scan_phase1(const float* __restrict__ proj, const float* __restrict__ dt,
                                                   const float* __restrict__ A, const u16* __restrict__ xs,
                                                   float* __restrict__ hloc, float* __restrict__ Ssum) {
    __shared__ float Bsh[TC][16];
    int d = blockIdx.x * 256 + threadIdx.x;
    int c = blockIdx.y, b = blockIdx.z;
    int t0 = c * TC;
    {   // stage B columns (proj[:, 64..79]) for this chunk: 64 rows x 16 floats
        int i = threadIdx.x >> 2;          // row 0..63
        int q = threadIdx.x & 3;           // 4 floats each
        const float* src = proj + ((size_t)b * SEQLEN + t0 + i) * NPROJ + DT_RANK + q * 4;
        *(float4*)&Bsh[i][q * 4] = *(const float4*)src;
    }
    __syncthreads();
    float Areg[16];
#pragma unroll
    for (int n = 0; n < 16; n++) Areg[n] = A[d * 16 + n];
    float h[16];
#pragma unroll
    for (int n = 0; n < 16; n++) h[n] = 0.f;
    float S = 0.f;
    size_t base = ((size_t)b * SEQLEN + t0) * D_INNER + d;
    for (int t = 0; t < TC; t++) {
        size_t idx = base + (size_t)t * D_INNER;
        float dtv = dt[idx];
        float u = bf2f(xs[idx]);
        S += dtv;
        float du = dtv * u;
#pragma unroll
        for (int n = 0; n < 16; n++) {
            h[n] = h[n] * __expf(dtv * Areg[n]) + du * Bsh[t][n];
        }
    }
    float* hp = &hloc[(((size_t)b * NC + c) * D_INNER + d) * 16];
#pragma unroll
    for (int n = 0; n < 16; n += 4)
        *(float4*)&hp[n] = make_float4(h[n], h[n + 1], h[n + 2], h[n + 3]);
    Ssum[((size_t)b * NC + c) * D_INNER + d] = S;
}

// ---------------------------------------------------------------------------
// K5b: combine chunks. Per (b,d,n) thread, serial over NC chunks, in-place:
// hloc[b][c][d][n] becomes h_init (state BEFORE chunk c).
__global__ __launch_bounds__(256) void scan_phase2(const float* __restrict__ A, const float* __restrict__ Ssum,
                                                   float* __restrict__ hloc) {
    int tid = blockIdx.x * 256 + threadIdx.x;   // 131072
    int n = tid & 15;
    int d = (tid >> 4) & (D_INNER - 1);
    int b = tid >> 16;
    float An = A[d * 16 + n];
    float h = 0.f;
    for (int c = 0; c < NC; c++) {
        size_t idx = (((size_t)b * NC + c) * D_INNER + d) * 16 + n;
        float hl = hloc[idx];
        float S = Ssum[((size_t)b * NC + c) * D_INNER + d];
        hloc[idx] = h;
        h = hl + h * __expf(An * S);
    }
}

// ---------------------------------------------------------------------------
// K5c: phase 3 — rerun chunk with h_init, compute y, D-residual, silu(z) gate.
// Writes gated y (bf16) over xs in place.
__global__ __launch_bounds__(256) void scan_phase3(const float* __restrict__ proj, const float* __restrict__ dt,
                                                   const float* __restrict__ A, const u16* __restrict__ D16,
                                                   const float* __restrict__ hinit, const u16* __restrict__ z16,
                                                   u16* __restrict__ xs) {
    __shared__ float BC[TC][32];  // [0..15]=B, [16..31]=C
    int d = blockIdx.x * 256 + threadIdx.x;
    int c = blockIdx.y, b = blockIdx.z;
    int t0 = c * TC;
    {   // stage B and C (proj[:, 64..95]) for this chunk: 64 rows x 32 floats
        int i = threadIdx.x >> 2;          // row 0..63
        int q = threadIdx.x & 3;           // 8 floats each
        const float* src = proj + ((size_t)b * SEQLEN + t0 + i) * NPROJ + DT_RANK + q * 8;
        *(float4*)&BC[i][q * 8 + 0] = *(const float4*)(src + 0);
        *(float4*)&BC[i][q * 8 + 4] = *(const float4*)(src + 4);
    }
    __syncthreads();
    float Areg[16];
#pragma unroll
    for (int n = 0; n < 16; n++) Areg[n] = A[d * 16 + n];
    float h[16];
    {
        const float* hp = &hinit[(((size_t)b * NC + c) * D_INNER + d) * 16];
#pragma unroll
        for (int n = 0; n < 16; n += 4) {
            float4 v = *(const float4*)&hp[n];
            h[n] = v.x; h[n + 1] = v.y; h[n + 2] = v.z; h[n + 3] = v.w;
        }
    }
    float Dd = bf2f(D16[d]);
    size_t base = ((size_t)b * SEQLEN + t0) * D_INNER + d;
    for (int t = 0; t < TC; t++) {
        size_t idx = base + (size_t)t * D_INNER;
        float dtv = dt[idx];
        float u = bf2f(xs[idx]);
        float zv = bf2f(z16[idx]);
        float du = dtv * u;
        float y = 0.f;
#pragma unroll
        for (int n = 0; n < 16; n++) {
            h[n] = h[n] * __expf(dtv * Areg[n]) + du * BC[t][n];
            y += h[n] * BC[t][16 + n];
        }
        float gate = zv / (1.f + __expf(-zv));
        xs[idx] = f2bf((y + u * Dd) * gate);
    }
}

// ---------------------------------------------------------------------------
// FALLBACK (round-2 path): fused serial scan, used if ws_size is too small.
__global__ __launch_bounds__(256) void ssm_scan(const float* __restrict__ proj, const float* __restrict__ A,
                                                const u16* __restrict__ dtw16, const u16* __restrict__ dtb16,
                                                const u16* __restrict__ D16, const u16* __restrict__ z16,
                                                u16* __restrict__ xs16) {
    __shared__ float pl[2][96];
    int tid = threadIdx.x;
    int n = tid & 15;
    int g = blockIdx.x * 16 + (tid >> 4);
    int d = g & (D_INNER - 1);
    int b = g >> 12;
    float An = A[d * D_STATE + n];
    float Dd = bf2f(D16[d]);
    float btd = bf2f(dtb16[d]);
    float w0 = bf2f(dtw16[(size_t)(4 * n + 0) * D_INNER + d]);
    float w1 = bf2f(dtw16[(size_t)(4 * n + 1) * D_INNER + d]);
    float w2 = bf2f(dtw16[(size_t)(4 * n + 2) * D_INNER + d]);
    float w3 = bf2f(dtw16[(size_t)(4 * n + 3) * D_INNER + d]);
    const float* prow = proj + (size_t)b * SEQLEN * NPROJ;
    size_t base = (size_t)b * SEQLEN * D_INNER + d;
    if (tid < NPROJ) pl[0][tid] = prow[tid];
    __syncthreads();
    float h = 0.f;
    for (int t = 0; t < SEQLEN; t++) {
        int cur = t & 1;
        float pre = 0.f;
        if (tid < NPROJ && t + 1 < SEQLEN) pre = prow[(size_t)(t + 1) * NPROJ + tid];
        float p0 = pl[cur][4 * n + 0], p1 = pl[cur][4 * n + 1];
        float p2 = pl[cur][4 * n + 2], p3 = pl[cur][4 * n + 3];
        float Bv = pl[cur][DT_RANK + n], Cv = pl[cur][DT_RANK + D_STATE + n];
        float part = w0 * p0 + w1 * p1 + w2 * p2 + w3 * p3;
        part += __shfl_xor(part, 1, 16);
        part += __shfl_xor(part, 2, 16);
        part += __shfl_xor(part, 4, 16);
        part += __shfl_xor(part, 8, 16);
        float dtv = softplusf(part + btd);
        size_t idx = base + (size_t)t * D_INNER;
        float u = bf2f(xs16[idx]);
        h = h * expf(dtv * An) + dtv * u * Bv;
        float p = h * Cv;
        p += __shfl_xor(p, 1, 16);
        p += __shfl_xor(p, 2, 16);
        p += __shfl_xor(p, 4, 16);
        p += __shfl_xor(p, 8, 16);
        if (n == 0) {
            float zv = bf2f(z16[idx]);
            float gate = zv / (1.f + expf(-zv));
            xs16[idx] = f2bf((p + u * Dd) * gate);
        }
        if (tid < NPROJ && t + 1 < SEQLEN) pl[1 - cur][tid] = pre;
        __syncthreads();
    }
}

// ---------------------------------------------------------------------------
// K6: out = y @ out_proj_w
__global__ __launch_bounds__(256) void gemm_out(const u16* __restrict__ Y, const void* __restrict__ Wv,
                                                void* __restrict__ out, const int* __restrict__ flag) {
    const int K = D_INNER, N = D_MODEL;
    __shared__ float As[16][65];
    __shared__ float Bs[16][64];
    int isb = *flag;
    int tid = threadIdx.x;
    int m0 = blockIdx.y * 64, n0 = blockIdx.x * 64;
    int tx = tid & 15, ty = tid >> 4;
    float acc[4][4] = {};
    for (int k0 = 0; k0 < K; k0 += 16) {
        {
            int l = tid * 4;
            int row = l >> 4, kk = l & 15;
            ushort4 av = *(const ushort4*)(&Y[(size_t)(m0 + row) * K + k0 + kk]);
            As[kk + 0][row] = bf2f(av.x);
            As[kk + 1][row] = bf2f(av.y);
            As[kk + 2][row] = bf2f(av.z);
            As[kk + 3][row] = bf2f(av.w);
        }
        {
            int l = tid * 4;
            int r = l >> 6, c = l & 63;
            size_t bi = (size_t)(k0 + r) * N + n0 + c;
            float4 bf4;
            if (isb) { ushort4 bv = *(const ushort4*)((const u16*)Wv + bi);
                       bf4 = make_float4(bf2f(bv.x), bf2f(bv.y), bf2f(bv.z), bf2f(bv.w)); }
            else     { bf4 = *(const float4*)((const float*)Wv + bi); }
            *(float4*)&Bs[r][c] = bf4;
        }
        __syncthreads();
#pragma unroll
        for (int kk = 0; kk < 16; kk++) {
            float a0 = As[kk][ty * 4 + 0], a1 = As[kk][ty * 4 + 1];
            float a2 = As[kk][ty * 4 + 2], a3 = As[kk][ty * 4 + 3];
            float4 b4 = *(float4*)&Bs[kk][tx * 4];
            acc[0][0] += a0 * b4.x; acc[0][1] += a0 * b4.y; acc[0][2] += a0 * b4.z; acc[0][3] += a0 * b4.w;
            acc[1][0] += a1 * b4.x; acc[1][1] += a1 * b4.y; acc[1][2] += a1 * b4.z; acc[1][3] += a1 * b4.w;
            acc[2][0] += a2 * b4.x; acc[2][1] += a2 * b4.y; acc[2][2] += a2 * b4.z; acc[2][3] += a2 * b4.w;
            acc[3][0] += a3 * b4.x; acc[3][1] += a3 * b4.y; acc[3][2] += a3 * b4.z; acc[3][3] += a3 * b4.w;
        }
        __syncthreads();
    }
#pragma unroll
    for (int i = 0; i < 4; i++) {
        int mm = m0 + ty * 4 + i;
#pragma unroll
        for (int j = 0; j < 4; j++) {
            int nn = n0 + tx * 4 + j;
            if (isb) ((u16*)out)[(size_t)mm * N + nn] = f2bf(acc[i][j]);
            else     ((float*)out)[(size_t)mm * N + nn] = acc[i][j];
        }
    }
}

// ---------------------------------------------------------------------------
extern "C" void kernel_launch(void* const* d_in, const int* in_sizes, int n_in,
                              void* d_out, int out_size, void* d_ws, size_t ws_size,
                              hipStream_t stream) {
    const void* x          = d_in[0];
    const void* in_proj_w  = d_in[1];
    const void* conv_w     = d_in[2];
    const void* conv_b     = d_in[3];
    const void* x_proj_w   = d_in[4];
    const void* dt_proj_w  = d_in[5];
    const void* dt_proj_b  = d_in[6];
    const void* A_log      = d_in[7];
    const void* Dvec       = d_in[8];
    const void* out_proj_w = d_in[9];

    char* w = (char*)d_ws;
    const size_t MB = 1024 * 1024;
    int*   flag  = (int*)(w + 0);
    float* Aws   = (float*)(w + 1024);
    float* proj  = (float*)(w + 1 * MB);
    u16*   cw16  = (u16*)(w + 3 * MB);
    u16*   cb16  = (u16*)(w + 3 * MB + 64 * 1024);
    u16*   xpw16 = (u16*)(w + 3 * MB + 128 * 1024);
    u16*   dtw16 = (u16*)(w + 4 * MB);
    u16*   dtb16 = (u16*)(w + 4 * MB + 600 * 1024);
    u16*   D16   = (u16*)(w + 4 * MB + 700 * 1024);
    u16*   buf1  = (u16*)(w + 5 * MB);           // 32 MiB : xc then z
    u16*   xs    = (u16*)(w + 37 * MB);          // 32 MiB : xs then gated y
    float* dtb_f = (float*)(w + 69 * MB);        // 64 MiB : dt fp32 [B*T, D]
    float* hloc  = (float*)(w + 133 * MB);       // 16 MiB : [B][NC][D][16]
    float* Ssum  = (float*)(w + 149 * MB);       // 1 MiB  : [B][NC][D]
    const size_t NEED = 150 * MB;
    bool chunked = (ws_size >= NEED);

    detect_dtype<<<dim3(1), dim3(256), 0, stream>>>((const u16*)x, flag);
    ingest16<<<dim3(64), dim3(256), 0, stream>>>(conv_w, cw16, D_INNER * D_CONV, flag);
    ingest16<<<dim3(16), dim3(256), 0, stream>>>(conv_b, cb16, D_INNER, flag);
    ingest16<<<dim3(1536), dim3(256), 0, stream>>>(x_proj_w, xpw16, D_INNER * NPROJ, flag);
    ingest16<<<dim3(1024), dim3(256), 0, stream>>>(dt_proj_w, dtw16, DT_RANK * D_INNER, flag);
    ingest16<<<dim3(16), dim3(256), 0, stream>>>(dt_proj_b, dtb16, D_INNER, flag);
    ingest16<<<dim3(16), dim3(256), 0, stream>>>(Dvec, D16, D_INNER, flag);
    prep_A<<<dim3(256), dim3(256), 0, stream>>>(A_log, Aws, flag);

    // K1a: xc half
    gemm_in<<<dim3(64, 64), dim3(256), 0, stream>>>(x, in_proj_w, buf1, 0, flag);
    // K2: conv + silu -> xs
    conv_silu<<<dim3(MROWS * D_INNER / 256), dim3(256), 0, stream>>>(buf1, cw16, cb16, xs);
    // K3: proj
    proj_gemm<<<dim3(MROWS / 8), dim3(128), 0, stream>>>(xs, xpw16, proj);
    // K1b: z half (overwrites xc, which is dead now)
    gemm_in<<<dim3(64, 64), dim3(256), 0, stream>>>(x, in_proj_w, buf1, D_INNER, flag);

    if (chunked) {
        // K4: dt fp32
        dt_gemm<<<dim3(D_INNER / 256, MROWS / 16), dim3(256), 0, stream>>>(proj, dtw16, dtb16, dtb_f);
        // K5: chunked scan
        scan_phase1<<<dim3(D_INNER / 256, NC, BATCH), dim3(256), 0, stream>>>(proj, dtb_f, Aws, xs, hloc, Ssum);
        scan_phase2<<<dim3(BATCH * D_INNER * D_STATE / 256), dim3(256), 0, stream>>>(Aws, Ssum, hloc);
        scan_phase3<<<dim3(D_INNER / 256, NC, BATCH), dim3(256), 0, stream>>>(proj, dtb_f, Aws, D16, hloc, buf1, xs);
    } else {
        // fallback: round-2 fused serial scan
        ssm_scan<<<dim3(512), dim3(256), 0, stream>>>(proj, Aws, dtw16, dtb16, D16, buf1, xs);
    }

    // K6: out
    gemm_out<<<dim3(D_MODEL / 64, MROWS / 64), dim3(256), 0, stream>>>(xs, out_proj_w, d_out, flag);
}

// Round 4
// 943.820 us; speedup vs baseline: 4.7527x; 2.2775x over previous
//
#include <hip/hip_runtime.h>
#include <hip/hip_bf16.h>

// Problem constants
#define D_MODEL 1024
#define D_INNER 4096
#define D_STATE 16
#define D_CONV 4
#define DT_RANK 64
#define BATCH 2
#define SEQLEN 2048
#define MROWS (BATCH * SEQLEN)          // 4096
#define NPROJ (DT_RANK + 2 * D_STATE)   // 96
#define NC 32                           // scan chunks
#define TC (SEQLEN / NC)                // 64 steps per chunk

typedef unsigned short u16;
typedef unsigned int u32;
typedef __attribute__((ext_vector_type(8))) short short8;
typedef __attribute__((ext_vector_type(4))) float floatx4;

__device__ __forceinline__ float bf2f(u16 u) {
    union { u32 i; float f; } v; v.i = ((u32)u) << 16; return v.f;
}
__device__ __forceinline__ u16 f2bf(float f) {
    union { float f; u32 i; } v; v.f = f;
    u32 x = v.i;
    u32 r = x + 0x7fffu + ((x >> 16) & 1u);   // round to nearest even
    return (u16)(r >> 16);
}
__device__ __forceinline__ float softplusf(float x) {
    return x > 0.f ? x + log1pf(expf(-x)) : log1pf(expf(x));
}
// async global->LDS 16B DMA (dest = wave-uniform base + lane*16)
__device__ __forceinline__ void async_cp16(const u16* g, u16* l) {
    __builtin_amdgcn_global_load_lds((const __attribute__((address_space(1))) void*)g,
                                     (__attribute__((address_space(3))) void*)l, 16, 0, 0);
}

// ---------------------------------------------------------------------------
// D0: detect input dtype (bf16 vs fp32) from exponent-field statistics.
__global__ __launch_bounds__(256) void detect_dtype(const u16* __restrict__ x, int* __restrict__ flag) {
    __shared__ int cnt;
    if (threadIdx.x == 0) cnt = 0;
    __syncthreads();
    int local = 0;
    for (int k = 0; k < 16; k++) {
        int e = threadIdx.x * 8192 + k * 512;
        u16 v = x[2 * e];
        int ex = (v >> 7) & 0xFF;
        if (ex >= 0x68 && ex <= 0x8F) local++;
    }
    atomicAdd(&cnt, local);
    __syncthreads();
    if (threadIdx.x == 0) *flag = (cnt >= 2458) ? 1 : 0;
}

// ---------------------------------------------------------------------------
__global__ __launch_bounds__(256) void ingest16(const void* __restrict__ src, u16* __restrict__ dst,
                                                int n, const int* __restrict__ flag) {
    int i = blockIdx.x * 256 + threadIdx.x;
    if (i >= n) return;
    if (*flag) dst[i] = ((const u16*)src)[i];
    else       dst[i] = f2bf(((const float*)src)[i]);
}

// ---------------------------------------------------------------------------
// Transpose-ingest: W [K][N] (dual dtype) -> WT [N][K] bf16.
__global__ __launch_bounds__(256) void transpose_w(const void* __restrict__ W, u16* __restrict__ WT,
                                                   int K, int N, const int* __restrict__ flag) {
    __shared__ float t[32][33];
    int k0 = blockIdx.y * 32, n0 = blockIdx.x * 32;
    int tid = threadIdx.x;
    int r = tid >> 3, c4 = (tid & 7) * 4;
    int isb = *flag;
    size_t base = (size_t)(k0 + r) * N + n0 + c4;
    float4 v;
    if (isb) { ushort4 u4 = *(const ushort4*)((const u16*)W + base);
               v = make_float4(bf2f(u4.x), bf2f(u4.y), bf2f(u4.z), bf2f(u4.w)); }
    else     { v = *(const float4*)((const float*)W + base); }
    t[c4 + 0][r] = v.x; t[c4 + 1][r] = v.y; t[c4 + 2][r] = v.z; t[c4 + 3][r] = v.w;
    __syncthreads();
    u16* o = WT + (size_t)(n0 + r) * K + k0 + c4;
    o[0] = f2bf(t[r][c4 + 0]);
    o[1] = f2bf(t[r][c4 + 1]);
    o[2] = f2bf(t[r][c4 + 2]);
    o[3] = f2bf(t[r][c4 + 3]);
}

// ---------------------------------------------------------------------------
__global__ __launch_bounds__(256) void prep_A(const void* __restrict__ A_log, float* __restrict__ A,
                                              const int* __restrict__ flag) {
    int i = blockIdx.x * 256 + threadIdx.x;
    if (i >= D_INNER * D_STATE) return;
    float v = (*flag) ? bf2f(((const u16*)A_log)[i]) : ((const float*)A_log)[i];
    A[i] = -expf(v);
}

// ---------------------------------------------------------------------------
// MFMA GEMM: C[M][N] = A[M][K] x Bt[N][K]^T.  bf16 in, fp32 accum.
// 128x128 tile, BK=32, 4 waves each computing 64x64 via 4x4 of 16x16x32.
// mode 0: bf16 store to dst.  mode 1: dual-dtype store per *flag.
__global__ __launch_bounds__(256) void gemm_bt(const u16* __restrict__ A, const u16* __restrict__ Bt,
                                               int K, void* __restrict__ dst, int ldd,
                                               int mode, const int* __restrict__ flag) {
    __shared__ __align__(16) u16 sA[128 * 32];   // [row 128][k 32]
    __shared__ __align__(16) u16 sB[128 * 32];   // [n 128][k 32]
    int tid = threadIdx.x;
    int lane = tid & 63;
    int wave = tid >> 6;
    int wm = (wave >> 1) * 64, wn = (wave & 1) * 64;
    int quad = lane >> 4, l15 = lane & 15;
    int m0 = blockIdx.y * 128, n0 = blockIdx.x * 128;

    floatx4 acc[4][4];
#pragma unroll
    for (int i = 0; i < 4; i++)
#pragma unroll
        for (int j = 0; j < 4; j++) acc[i][j] = (floatx4)0.f;

    // staging: chunk c = iter*256 + tid; row = c>>2, kchunk = c&3 (8 bf16 per 16B)
    const u16* ga0 = A + (size_t)(m0 + (tid >> 2)) * K + (tid & 3) * 8;
    const u16* ga1 = A + (size_t)(m0 + 64 + (tid >> 2)) * K + (tid & 3) * 8;
    const u16* gb0 = Bt + (size_t)(n0 + (tid >> 2)) * K + (tid & 3) * 8;
    const u16* gb1 = Bt + (size_t)(n0 + 64 + (tid >> 2)) * K + (tid & 3) * 8;
    u16* la0 = &sA[tid * 8];
    u16* la1 = &sA[(256 + tid) * 8];
    u16* lb0 = &sB[tid * 8];
    u16* lb1 = &sB[(256 + tid) * 8];

    for (int k0 = 0; k0 < K; k0 += 32) {
        async_cp16(ga0 + k0, la0);
        async_cp16(ga1 + k0, la1);
        async_cp16(gb0 + k0, lb0);
        async_cp16(gb1 + k0, lb1);
        __syncthreads();   // compiler emits vmcnt(0) drain before barrier
        short8 af[4], bf[4];
#pragma unroll
        for (int i = 0; i < 4; i++) {
            af[i] = *(const short8*)&sA[(wm + i * 16 + l15) * 32 + quad * 8];
            bf[i] = *(const short8*)&sB[(wn + i * 16 + l15) * 32 + quad * 8];
        }
#pragma unroll
        for (int i = 0; i < 4; i++)
#pragma unroll
            for (int j = 0; j < 4; j++)
                acc[i][j] = __builtin_amdgcn_mfma_f32_16x16x32_bf16(af[i], bf[j], acc[i][j], 0, 0, 0);
        __syncthreads();
    }

    // C/D layout (verified m89/m91): col = lane&15, row = quad*4 + reg
    if (mode == 0 || *flag) {
        u16* d = (u16*)dst;
#pragma unroll
        for (int i = 0; i < 4; i++)
#pragma unroll
            for (int j = 0; j < 4; j++)
#pragma unroll
                for (int r = 0; r < 4; r++) {
                    int mm = m0 + wm + i * 16 + quad * 4 + r;
                    int nn = n0 + wn + j * 16 + l15;
                    d[(size_t)mm * ldd + nn] = f2bf(acc[i][j][r]);
                }
    } else {
        float* d = (float*)dst;
#pragma unroll
        for (int i = 0; i < 4; i++)
#pragma unroll
            for (int j = 0; j < 4; j++)
#pragma unroll
                for (int r = 0; r < 4; r++) {
                    int mm = m0 + wm + i * 16 + quad * 4 + r;
                    int nn = n0 + wn + j * 16 + l15;
                    d[(size_t)mm * ldd + nn] = acc[i][j][r];
                }
    }
}

// ---------------------------------------------------------------------------
// K2: causal depthwise conv1d + silu (bf16 in/out)
__global__ __launch_bounds__(256) void conv_silu(const u16* __restrict__ xc, const u16* __restrict__ cw,
                                                 const u16* __restrict__ cb, u16* __restrict__ xs) {
    int idx = blockIdx.x * 256 + threadIdx.x;
    int d = idx & (D_INNER - 1);
    int t = (idx >> 12) & (SEQLEN - 1);
    int b = idx >> 23;
    float w0 = bf2f(cw[d * 4 + 0]), w1 = bf2f(cw[d * 4 + 1]);
    float w2 = bf2f(cw[d * 4 + 2]), w3 = bf2f(cw[d * 4 + 3]);
    float acc = bf2f(cb[d]);
    size_t base = (size_t)b * SEQLEN * D_INNER + d;
    if (t >= 3) acc += bf2f(xc[base + (size_t)(t - 3) * D_INNER]) * w0;
    if (t >= 2) acc += bf2f(xc[base + (size_t)(t - 2) * D_INNER]) * w1;
    if (t >= 1) acc += bf2f(xc[base + (size_t)(t - 1) * D_INNER]) * w2;
    acc += bf2f(xc[base + (size_t)t * D_INNER]) * w3;
    float s = acc / (1.f + expf(-acc));
    xs[idx] = f2bf(s);
}

// ---------------------------------------------------------------------------
// K3: proj = xs @ x_proj_w   [4096,4096] x [4096,96] -> fp32
__global__ __launch_bounds__(128) void proj_gemm(const u16* __restrict__ xs, const u16* __restrict__ W,
                                                 float* __restrict__ proj) {
    __shared__ float xt[8][64];
    int m0 = blockIdx.x * 8;
    int tid = threadIdx.x;
    int j = tid;
    float acc[8] = {};
    for (int k0 = 0; k0 < D_INNER; k0 += 64) {
        int l = tid * 4;
        int r = l >> 6, c = l & 63;
        ushort4 v = *(const ushort4*)(&xs[(size_t)(m0 + r) * D_INNER + k0 + c]);
        xt[r][c + 0] = bf2f(v.x); xt[r][c + 1] = bf2f(v.y);
        xt[r][c + 2] = bf2f(v.z); xt[r][c + 3] = bf2f(v.w);
        __syncthreads();
        if (j < NPROJ) {
            for (int kk = 0; kk < 64; kk++) {
                float w = bf2f(W[(size_t)(k0 + kk) * NPROJ + j]);
#pragma unroll
                for (int r2 = 0; r2 < 8; r2++) acc[r2] += xt[r2][kk] * w;
            }
        }
        __syncthreads();
    }
    if (j < NPROJ) {
#pragma unroll
        for (int r2 = 0; r2 < 8; r2++) proj[(size_t)(m0 + r2) * NPROJ + j] = acc[r2];
    }
}

// ---------------------------------------------------------------------------
// K4: dt = softplus(proj[:, :64] @ dt_proj_w + dt_proj_b) -> bf16 [B*T, D]
__global__ __launch_bounds__(256) void dt_gemm(const float* __restrict__ proj, const u16* __restrict__ dtW,
                                               const u16* __restrict__ dtb, u16* __restrict__ dt) {
    __shared__ float pl[16][64];
    int d = blockIdx.x * 256 + threadIdx.x;
    int m0 = blockIdx.y * 16;
    {
        int l = threadIdx.x * 4;
        int r = l >> 6, c = l & 63;
        float4 v = *(const float4*)(&proj[(size_t)(m0 + r) * NPROJ + c]);
        *(float4*)&pl[r][c] = v;
    }
    __syncthreads();
    float acc[16] = {};
    for (int r2 = 0; r2 < 64; r2++) {
        float w = bf2f(dtW[(size_t)r2 * D_INNER + d]);
#pragma unroll
        for (int i = 0; i < 16; i++) acc[i] += pl[i][r2] * w;
    }
    float b = bf2f(dtb[d]);
#pragma unroll
    for (int i = 0; i < 16; i++) {
        dt[(size_t)(m0 + i) * D_INNER + d] = f2bf(softplusf(acc[i] + b));
    }
}

// ---------------------------------------------------------------------------
// K5a: chunked scan phase 1 — per (b,d,chunk) thread, 16 states in registers.
__global__ __launch_bounds__(256) void scan_phase1(const float* __restrict__ proj, const u16* __restrict__ dt,
                                                   const float* __restrict__ A, const u16* __restrict__ xs,
                                                   float* __restrict__ hloc, float* __restrict__ Ssum) {
    __shared__ float Bsh[TC][16];
    int d = blockIdx.x * 256 + threadIdx.x;
    int c = blockIdx.y, b = blockIdx.z;
    int t0 = c * TC;
    {
        int i = threadIdx.x >> 2;
        int q = threadIdx.x & 3;
        const float* src = proj + ((size_t)b * SEQLEN + t0 + i) * NPROJ + DT_RANK + q * 4;
        *(float4*)&Bsh[i][q * 4] = *(const float4*)src;
    }
    __syncthreads();
    float Areg[16];
#pragma unroll
    for (int n = 0; n < 16; n++) Areg[n] = A[d * 16 + n];
    float h[16];
#pragma unroll
    for (int n = 0; n < 16; n++) h[n] = 0.f;
    float S = 0.f;
    size_t base = ((size_t)b * SEQLEN + t0) * D_INNER + d;
    for (int t = 0; t < TC; t++) {
        size_t idx = base + (size_t)t * D_INNER;
        float dtv = bf2f(dt[idx]);
        float u = bf2f(xs[idx]);
        S += dtv;
        float du = dtv * u;
#pragma unroll
        for (int n = 0; n < 16; n++) {
            h[n] = h[n] * __expf(dtv * Areg[n]) + du * Bsh[t][n];
        }
    }
    float* hp = &hloc[(((size_t)b * NC + c) * D_INNER + d) * 16];
#pragma unroll
    for (int n = 0; n < 16; n += 4)
        *(float4*)&hp[n] = make_float4(h[n], h[n + 1], h[n + 2], h[n + 3]);
    Ssum[((size_t)b * NC + c) * D_INNER + d] = S;
}

// ---------------------------------------------------------------------------
// K5b: combine chunks serially (in place: hloc becomes h_init per chunk).
__global__ __launch_bounds__(256) void scan_phase2(const float* __restrict__ A, const float* __restrict__ Ssum,
                                                   float* __restrict__ hloc) {
    int tid = blockIdx.x * 256 + threadIdx.x;
    int n = tid & 15;
    int d = (tid >> 4) & (D_INNER - 1);
    int b = tid >> 16;
    float An = A[d * 16 + n];
    float h = 0.f;
    for (int c = 0; c < NC; c++) {
        size_t idx = (((size_t)b * NC + c) * D_INNER + d) * 16 + n;
        float hl = hloc[idx];
        float S = Ssum[((size_t)b * NC + c) * D_INNER + d];
        hloc[idx] = h;
        h = hl + h * __expf(An * S);
    }
}

// ---------------------------------------------------------------------------
// K5c: phase 3 — rerun chunk with h_init, compute y, D-residual, silu(z) gate.
__global__ __launch_bounds__(256) void scan_phase3(const float* __restrict__ proj, const u16* __restrict__ dt,
                                                   const float* __restrict__ A, const u16* __restrict__ D16,
                                                   const float* __restrict__ hinit, const u16* __restrict__ z16,
                                                   u16* __restrict__ xs) {
    __shared__ float BC[TC][32];
    int d = blockIdx.x * 256 + threadIdx.x;
    int c = blockIdx.y, b = blockIdx.z;
    int t0 = c * TC;
    {
        int i = threadIdx.x >> 2;
        int q = threadIdx.x & 3;
        const float* src = proj + ((size_t)b * SEQLEN + t0 + i) * NPROJ + DT_RANK + q * 8;
        *(float4*)&BC[i][q * 8 + 0] = *(const float4*)(src + 0);
        *(float4*)&BC[i][q * 8 + 4] = *(const float4*)(src + 4);
    }
    __syncthreads();
    float Areg[16];
#pragma unroll
    for (int n = 0; n < 16; n++) Areg[n] = A[d * 16 + n];
    float h[16];
    {
        const float* hp = &hinit[(((size_t)b * NC + c) * D_INNER + d) * 16];
#pragma unroll
        for (int n = 0; n < 16; n += 4) {
            float4 v = *(const float4*)&hp[n];
            h[n] = v.x; h[n + 1] = v.y; h[n + 2] = v.z; h[n + 3] = v.w;
        }
    }
    float Dd = bf2f(D16[d]);
    size_t base = ((size_t)b * SEQLEN + t0) * D_INNER + d;
    for (int t = 0; t < TC; t++) {
        size_t idx = base + (size_t)t * D_INNER;
        float dtv = bf2f(dt[idx]);
        float u = bf2f(xs[idx]);
        float zv = bf2f(z16[idx]);
        float du = dtv * u;
        float y = 0.f;
#pragma unroll
        for (int n = 0; n < 16; n++) {
            h[n] = h[n] * __expf(dtv * Areg[n]) + du * BC[t][n];
            y += h[n] * BC[t][16 + n];
        }
        float gate = zv / (1.f + __expf(-zv));
        xs[idx] = f2bf((y + u * Dd) * gate);
    }
}

// ---------------------------------------------------------------------------
extern "C" void kernel_launch(void* const* d_in, const int* in_sizes, int n_in,
                              void* d_out, int out_size, void* d_ws, size_t ws_size,
                              hipStream_t stream) {
    const void* x          = d_in[0];
    const void* in_proj_w  = d_in[1];
    const void* conv_w     = d_in[2];
    const void* conv_b     = d_in[3];
    const void* x_proj_w   = d_in[4];
    const void* dt_proj_w  = d_in[5];
    const void* dt_proj_b  = d_in[6];
    const void* A_log      = d_in[7];
    const void* Dvec       = d_in[8];
    const void* out_proj_w = d_in[9];

    char* w = (char*)d_ws;
    const size_t MB = 1024 * 1024;
    int*   flag  = (int*)(w + 0);
    float* Aws   = (float*)(w + 1024);
    float* proj  = (float*)(w + 1 * MB);
    u16*   cw16  = (u16*)(w + 3 * MB);
    u16*   cb16  = (u16*)(w + 3 * MB + 64 * 1024);
    u16*   xpw16 = (u16*)(w + 3 * MB + 128 * 1024);
    u16*   dtw16 = (u16*)(w + 4 * MB);
    u16*   dtb16 = (u16*)(w + 4 * MB + 600 * 1024);
    u16*   D16   = (u16*)(w + 4 * MB + 700 * 1024);
    u16*   buf1  = (u16*)(w + 5 * MB);     // 32 MB: xc then z
    u16*   xs    = (u16*)(w + 37 * MB);    // 32 MB: xs then gated y
    u16*   dt16  = (u16*)(w + 69 * MB);    // 32 MB (overlays x16/ipwT after they die)
    u16*   x16   = (u16*)(w + 69 * MB);    // 8.4 MB
    u16*   ipwT  = (u16*)(w + 78 * MB);    // 16.8 MB: in_proj_w^T [8192][1024]
    float* hloc  = (float*)(w + 101 * MB); // 16 MB
    float* Ssum  = (float*)(w + 117 * MB); // 1 MB
    u16*   opwT  = (u16*)(w + 118 * MB);   // 8.4 MB: out_proj_w^T [1024][4096]
    // total 127 MB (<150 MB proven available)

    detect_dtype<<<dim3(1), dim3(256), 0, stream>>>((const u16*)x, flag);
    ingest16<<<dim3(64), dim3(256), 0, stream>>>(conv_w, cw16, D_INNER * D_CONV, flag);
    ingest16<<<dim3(16), dim3(256), 0, stream>>>(conv_b, cb16, D_INNER, flag);
    ingest16<<<dim3(1536), dim3(256), 0, stream>>>(x_proj_w, xpw16, D_INNER * NPROJ, flag);
    ingest16<<<dim3(1024), dim3(256), 0, stream>>>(dt_proj_w, dtw16, DT_RANK * D_INNER, flag);
    ingest16<<<dim3(16), dim3(256), 0, stream>>>(dt_proj_b, dtb16, D_INNER, flag);
    ingest16<<<dim3(16), dim3(256), 0, stream>>>(Dvec, D16, D_INNER, flag);
    prep_A<<<dim3(256), dim3(256), 0, stream>>>(A_log, Aws, flag);
    ingest16<<<dim3(MROWS * D_MODEL / 256), dim3(256), 0, stream>>>(x, x16, MROWS * D_MODEL, flag);
    transpose_w<<<dim3(2 * D_INNER / 32, D_MODEL / 32), dim3(256), 0, stream>>>(in_proj_w, ipwT, D_MODEL, 2 * D_INNER, flag);
    transpose_w<<<dim3(D_MODEL / 32, D_INNER / 32), dim3(256), 0, stream>>>(out_proj_w, opwT, D_INNER, D_MODEL, flag);

    // K1a: xc = x @ Win[:, :4096]
    gemm_bt<<<dim3(D_INNER / 128, MROWS / 128), dim3(256), 0, stream>>>(
        x16, ipwT, D_MODEL, buf1, D_INNER, 0, flag);
    // K2: conv + silu -> xs
    conv_silu<<<dim3(MROWS * D_INNER / 256), dim3(256), 0, stream>>>(buf1, cw16, cb16, xs);
    // K1b: z = x @ Win[:, 4096:]  (overwrites xc, dead after conv)
    gemm_bt<<<dim3(D_INNER / 128, MROWS / 128), dim3(256), 0, stream>>>(
        x16, ipwT + (size_t)D_INNER * D_MODEL, D_MODEL, buf1, D_INNER, 0, flag);
    // K3: proj
    proj_gemm<<<dim3(MROWS / 8), dim3(128), 0, stream>>>(xs, xpw16, proj);
    // K4: dt bf16 (overwrites x16/ipwT region - both dead)
    dt_gemm<<<dim3(D_INNER / 256, MROWS / 16), dim3(256), 0, stream>>>(proj, dtw16, dtb16, dt16);
    // K5: chunked scan
    scan_phase1<<<dim3(D_INNER / 256, NC, BATCH), dim3(256), 0, stream>>>(proj, dt16, Aws, xs, hloc, Ssum);
    scan_phase2<<<dim3(BATCH * D_INNER * D_STATE / 256), dim3(256), 0, stream>>>(Aws, Ssum, hloc);
    scan_phase3<<<dim3(D_INNER / 256, NC, BATCH), dim3(256), 0, stream>>>(proj, dt16, Aws, D16, hloc, buf1, xs);
    // K6: out = y @ out_proj_w
    gemm_bt<<<dim3(D_MODEL / 128, MROWS / 128), dim3(256), 0, stream>>>(
        xs, opwT, D_INNER, d_out, D_MODEL, 1, flag);
}

// Round 5
// 666.039 us; speedup vs baseline: 6.7349x; 1.4171x over previous
//
#include <hip/hip_runtime.h>
#include <hip/hip_bf16.h>

// Problem constants
#define D_MODEL 1024
#define D_INNER 4096
#define D_STATE 16
#define D_CONV 4
#define DT_RANK 64
#define BATCH 2
#define SEQLEN 2048
#define MROWS (BATCH * SEQLEN)          // 4096
#define NPROJ (DT_RANK + 2 * D_STATE)   // 96
#define PST 128                         // proj row stride (padded, fp32)
#define NC 32                           // scan chunks
#define TC (SEQLEN / NC)                // 64 steps per chunk
#define KSPLIT 8                        // split-K for proj gemm

typedef unsigned short u16;
typedef unsigned int u32;
typedef __attribute__((ext_vector_type(8))) short short8;
typedef __attribute__((ext_vector_type(4))) float floatx4;

__device__ __forceinline__ float bf2f(u16 u) {
    union { u32 i; float f; } v; v.i = ((u32)u) << 16; return v.f;
}
__device__ __forceinline__ u16 f2bf(float f) {
    union { float f; u32 i; } v; v.f = f;
    u32 x = v.i;
    u32 r = x + 0x7fffu + ((x >> 16) & 1u);   // round to nearest even
    return (u16)(r >> 16);
}
__device__ __forceinline__ float softplusf(float x) {
    return x > 0.f ? x + log1pf(expf(-x)) : log1pf(expf(x));
}
// async global->LDS 16B DMA (dest = wave-uniform base + lane*16)
__device__ __forceinline__ void async_cp16(const u16* g, u16* l) {
    __builtin_amdgcn_global_load_lds((const __attribute__((address_space(1))) void*)g,
                                     (__attribute__((address_space(3))) void*)l, 16, 0, 0);
}

// ---------------------------------------------------------------------------
// D0: detect input dtype (bf16 vs fp32) from exponent-field statistics.
__global__ __launch_bounds__(256) void detect_dtype(const u16* __restrict__ x, int* __restrict__ flag) {
    __shared__ int cnt;
    if (threadIdx.x == 0) cnt = 0;
    __syncthreads();
    int local = 0;
    for (int k = 0; k < 16; k++) {
        int e = threadIdx.x * 8192 + k * 512;
        u16 v = x[2 * e];
        int ex = (v >> 7) & 0xFF;
        if (ex >= 0x68 && ex <= 0x8F) local++;
    }
    atomicAdd(&cnt, local);
    __syncthreads();
    if (threadIdx.x == 0) *flag = (cnt >= 2458) ? 1 : 0;
}

// ---------------------------------------------------------------------------
__global__ __launch_bounds__(256) void ingest16(const void* __restrict__ src, u16* __restrict__ dst,
                                                int n, const int* __restrict__ flag) {
    int i = blockIdx.x * 256 + threadIdx.x;
    if (i >= n) return;
    if (*flag) dst[i] = ((const u16*)src)[i];
    else       dst[i] = f2bf(((const float*)src)[i]);
}

// ---------------------------------------------------------------------------
// Transpose-ingest: W [K][N] (dual dtype) -> WT [N][K] bf16.
__global__ __launch_bounds__(256) void transpose_w(const void* __restrict__ W, u16* __restrict__ WT,
                                                   int K, int N, const int* __restrict__ flag) {
    __shared__ float t[32][33];
    int k0 = blockIdx.y * 32, n0 = blockIdx.x * 32;
    int tid = threadIdx.x;
    int r = tid >> 3, c4 = (tid & 7) * 4;
    int isb = *flag;
    size_t base = (size_t)(k0 + r) * N + n0 + c4;
    float4 v;
    if (isb) { ushort4 u4 = *(const ushort4*)((const u16*)W + base);
               v = make_float4(bf2f(u4.x), bf2f(u4.y), bf2f(u4.z), bf2f(u4.w)); }
    else     { v = *(const float4*)((const float*)W + base); }
    t[c4 + 0][r] = v.x; t[c4 + 1][r] = v.y; t[c4 + 2][r] = v.z; t[c4 + 3][r] = v.w;
    __syncthreads();
    u16* o = WT + (size_t)(n0 + r) * K + k0 + c4;
    o[0] = f2bf(t[r][c4 + 0]);
    o[1] = f2bf(t[r][c4 + 1]);
    o[2] = f2bf(t[r][c4 + 2]);
    o[3] = f2bf(t[r][c4 + 3]);
}

// ---------------------------------------------------------------------------
__global__ __launch_bounds__(256) void prep_A(const void* __restrict__ A_log, float* __restrict__ A,
                                              const int* __restrict__ flag) {
    int i = blockIdx.x * 256 + threadIdx.x;
    if (i >= D_INNER * D_STATE) return;
    float v = (*flag) ? bf2f(((const u16*)A_log)[i]) : ((const float*)A_log)[i];
    A[i] = -expf(v);
}

// ---------------------------------------------------------------------------
// MFMA GEMM: C[M][N] = A[M][K] x Bt[N][K]^T.  bf16 in, fp32 accum.
// 128x128 tile, BK=32, 4 waves each computing 64x64 via 4x4 of 16x16x32.
// mode 0: bf16 store to dst.  mode 1: dual-dtype store per *flag.
__global__ __launch_bounds__(256) void gemm_bt(const u16* __restrict__ A, const u16* __restrict__ Bt,
                                               int K, void* __restrict__ dst, int ldd,
                                               int mode, const int* __restrict__ flag) {
    __shared__ __align__(16) u16 sA[128 * 32];   // [row 128][k 32]
    __shared__ __align__(16) u16 sB[128 * 32];   // [n 128][k 32]
    int tid = threadIdx.x;
    int lane = tid & 63;
    int wave = tid >> 6;
    int wm = (wave >> 1) * 64, wn = (wave & 1) * 64;
    int quad = lane >> 4, l15 = lane & 15;
    int m0 = blockIdx.y * 128, n0 = blockIdx.x * 128;

    floatx4 acc[4][4];
#pragma unroll
    for (int i = 0; i < 4; i++)
#pragma unroll
        for (int j = 0; j < 4; j++) acc[i][j] = (floatx4)0.f;

    const u16* ga0 = A + (size_t)(m0 + (tid >> 2)) * K + (tid & 3) * 8;
    const u16* ga1 = A + (size_t)(m0 + 64 + (tid >> 2)) * K + (tid & 3) * 8;
    const u16* gb0 = Bt + (size_t)(n0 + (tid >> 2)) * K + (tid & 3) * 8;
    const u16* gb1 = Bt + (size_t)(n0 + 64 + (tid >> 2)) * K + (tid & 3) * 8;
    u16* la0 = &sA[tid * 8];
    u16* la1 = &sA[(256 + tid) * 8];
    u16* lb0 = &sB[tid * 8];
    u16* lb1 = &sB[(256 + tid) * 8];

    for (int k0 = 0; k0 < K; k0 += 32) {
        async_cp16(ga0 + k0, la0);
        async_cp16(ga1 + k0, la1);
        async_cp16(gb0 + k0, lb0);
        async_cp16(gb1 + k0, lb1);
        __syncthreads();
        short8 af[4], bf[4];
#pragma unroll
        for (int i = 0; i < 4; i++) {
            af[i] = *(const short8*)&sA[(wm + i * 16 + l15) * 32 + quad * 8];
            bf[i] = *(const short8*)&sB[(wn + i * 16 + l15) * 32 + quad * 8];
        }
#pragma unroll
        for (int i = 0; i < 4; i++)
#pragma unroll
            for (int j = 0; j < 4; j++)
                acc[i][j] = __builtin_amdgcn_mfma_f32_16x16x32_bf16(af[i], bf[j], acc[i][j], 0, 0, 0);
        __syncthreads();
    }

    // C/D layout: col = lane&15, row = quad*4 + reg
    if (mode == 0 || *flag) {
        u16* d = (u16*)dst;
#pragma unroll
        for (int i = 0; i < 4; i++)
#pragma unroll
            for (int j = 0; j < 4; j++)
#pragma unroll
                for (int r = 0; r < 4; r++) {
                    int mm = m0 + wm + i * 16 + quad * 4 + r;
                    int nn = n0 + wn + j * 16 + l15;
                    d[(size_t)mm * ldd + nn] = f2bf(acc[i][j][r]);
                }
    } else {
        float* d = (float*)dst;
#pragma unroll
        for (int i = 0; i < 4; i++)
#pragma unroll
            for (int j = 0; j < 4; j++)
#pragma unroll
                for (int r = 0; r < 4; r++) {
                    int mm = m0 + wm + i * 16 + quad * 4 + r;
                    int nn = n0 + wn + j * 16 + l15;
                    d[(size_t)mm * ldd + nn] = acc[i][j][r];
                }
    }
}

// ---------------------------------------------------------------------------
// K3: proj split-K MFMA.  A = xs [4096][4096], Bt = xpwT [128(pad)][4096].
// grid (KSPLIT, M/128).  Each block does K range of 4096/KSPLIT, writes fp32
// partial [kz][M][PST].  Cols 96..127 are garbage (never read downstream).
__global__ __launch_bounds__(256) void gemm_proj(const u16* __restrict__ A, const u16* __restrict__ Bt,
                                                 float* __restrict__ Pp) {
    const int K = D_INNER;
    __shared__ __align__(16) u16 sA[128 * 32];
    __shared__ __align__(16) u16 sB[128 * 32];
    int tid = threadIdx.x;
    int lane = tid & 63;
    int wave = tid >> 6;
    int wm = (wave >> 1) * 64, wn = (wave & 1) * 64;
    int quad = lane >> 4, l15 = lane & 15;
    int m0 = blockIdx.y * 128;
    int kz = blockIdx.x;
    int kbase = kz * (K / KSPLIT);

    floatx4 acc[4][4];
#pragma unroll
    for (int i = 0; i < 4; i++)
#pragma unroll
        for (int j = 0; j < 4; j++) acc[i][j] = (floatx4)0.f;

    const u16* ga0 = A + (size_t)(m0 + (tid >> 2)) * K + (tid & 3) * 8;
    const u16* ga1 = A + (size_t)(m0 + 64 + (tid >> 2)) * K + (tid & 3) * 8;
    const u16* gb0 = Bt + (size_t)(tid >> 2) * K + (tid & 3) * 8;
    const u16* gb1 = Bt + (size_t)(64 + (tid >> 2)) * K + (tid & 3) * 8;
    u16* la0 = &sA[tid * 8];
    u16* la1 = &sA[(256 + tid) * 8];
    u16* lb0 = &sB[tid * 8];
    u16* lb1 = &sB[(256 + tid) * 8];

    for (int k0 = kbase; k0 < kbase + K / KSPLIT; k0 += 32) {
        async_cp16(ga0 + k0, la0);
        async_cp16(ga1 + k0, la1);
        async_cp16(gb0 + k0, lb0);
        async_cp16(gb1 + k0, lb1);
        __syncthreads();
        short8 af[4], bf[4];
#pragma unroll
        for (int i = 0; i < 4; i++) {
            af[i] = *(const short8*)&sA[(wm + i * 16 + l15) * 32 + quad * 8];
            bf[i] = *(const short8*)&sB[(wn + i * 16 + l15) * 32 + quad * 8];
        }
#pragma unroll
        for (int i = 0; i < 4; i++)
#pragma unroll
            for (int j = 0; j < 4; j++)
                acc[i][j] = __builtin_amdgcn_mfma_f32_16x16x32_bf16(af[i], bf[j], acc[i][j], 0, 0, 0);
        __syncthreads();
    }

    float* d = Pp + (size_t)kz * MROWS * PST;
#pragma unroll
    for (int i = 0; i < 4; i++)
#pragma unroll
        for (int j = 0; j < 4; j++)
#pragma unroll
            for (int r = 0; r < 4; r++) {
                int mm = m0 + wm + i * 16 + quad * 4 + r;
                int nn = wn + j * 16 + l15;
                d[(size_t)mm * PST + nn] = acc[i][j][r];
            }
}

// ---------------------------------------------------------------------------
__global__ __launch_bounds__(256) void reduce_proj(const float* __restrict__ Pp, float* __restrict__ proj) {
    int i = blockIdx.x * 256 + threadIdx.x;    // < MROWS*PST
    float s = 0.f;
#pragma unroll
    for (int z = 0; z < KSPLIT; z++) s += Pp[(size_t)z * MROWS * PST + i];
    proj[i] = s;
}

// ---------------------------------------------------------------------------
// K2: causal depthwise conv1d + silu (bf16 in/out)
__global__ __launch_bounds__(256) void conv_silu(const u16* __restrict__ xc, const u16* __restrict__ cw,
                                                 const u16* __restrict__ cb, u16* __restrict__ xs) {
    int idx = blockIdx.x * 256 + threadIdx.x;
    int d = idx & (D_INNER - 1);
    int t = (idx >> 12) & (SEQLEN - 1);
    int b = idx >> 23;
    float w0 = bf2f(cw[d * 4 + 0]), w1 = bf2f(cw[d * 4 + 1]);
    float w2 = bf2f(cw[d * 4 + 2]), w3 = bf2f(cw[d * 4 + 3]);
    float acc = bf2f(cb[d]);
    size_t base = (size_t)b * SEQLEN * D_INNER + d;
    if (t >= 3) acc += bf2f(xc[base + (size_t)(t - 3) * D_INNER]) * w0;
    if (t >= 2) acc += bf2f(xc[base + (size_t)(t - 2) * D_INNER]) * w1;
    if (t >= 1) acc += bf2f(xc[base + (size_t)(t - 1) * D_INNER]) * w2;
    acc += bf2f(xc[base + (size_t)t * D_INNER]) * w3;
    float s = acc / (1.f + expf(-acc));
    xs[idx] = f2bf(s);
}

// ---------------------------------------------------------------------------
// K4: dt = softplus(proj[:, :64] @ dt_proj_w + dt_proj_b) -> bf16 [B*T, D]
__global__ __launch_bounds__(256) void dt_gemm(const float* __restrict__ proj, const u16* __restrict__ dtW,
                                               const u16* __restrict__ dtb, u16* __restrict__ dt) {
    __shared__ float pl[16][64];
    int d = blockIdx.x * 256 + threadIdx.x;
    int m0 = blockIdx.y * 16;
    {
        int l = threadIdx.x * 4;
        int r = l >> 6, c = l & 63;
        float4 v = *(const float4*)(&proj[(size_t)(m0 + r) * PST + c]);
        *(float4*)&pl[r][c] = v;
    }
    __syncthreads();
    float acc[16] = {};
    for (int r2 = 0; r2 < 64; r2++) {
        float w = bf2f(dtW[(size_t)r2 * D_INNER + d]);
#pragma unroll
        for (int i = 0; i < 16; i++) acc[i] += pl[i][r2] * w;
    }
    float b = bf2f(dtb[d]);
#pragma unroll
    for (int i = 0; i < 16; i++) {
        dt[(size_t)(m0 + i) * D_INNER + d] = f2bf(softplusf(acc[i] + b));
    }
}

// ---------------------------------------------------------------------------
// K5a: chunked scan phase 1 — per (b,d,chunk) thread, 16 states in registers.
__global__ __launch_bounds__(256) void scan_phase1(const float* __restrict__ proj, const u16* __restrict__ dt,
                                                   const float* __restrict__ A, const u16* __restrict__ xs,
                                                   float* __restrict__ hloc, float* __restrict__ Ssum) {
    __shared__ float Bsh[TC][16];
    int d = blockIdx.x * 256 + threadIdx.x;
    int c = blockIdx.y, b = blockIdx.z;
    int t0 = c * TC;
    {
        int i = threadIdx.x >> 2;
        int q = threadIdx.x & 3;
        const float* src = proj + ((size_t)b * SEQLEN + t0 + i) * PST + DT_RANK + q * 4;
        *(float4*)&Bsh[i][q * 4] = *(const float4*)src;
    }
    __syncthreads();
    float Areg[16];
#pragma unroll
    for (int n = 0; n < 16; n++) Areg[n] = A[d * 16 + n];
    float h[16];
#pragma unroll
    for (int n = 0; n < 16; n++) h[n] = 0.f;
    float S = 0.f;
    size_t base = ((size_t)b * SEQLEN + t0) * D_INNER + d;
    for (int t = 0; t < TC; t++) {
        size_t idx = base + (size_t)t * D_INNER;
        float dtv = bf2f(dt[idx]);
        float u = bf2f(xs[idx]);
        S += dtv;
        float du = dtv * u;
#pragma unroll
        for (int n = 0; n < 16; n++) {
            h[n] = h[n] * __expf(dtv * Areg[n]) + du * Bsh[t][n];
        }
    }
    float* hp = &hloc[(((size_t)b * NC + c) * D_INNER + d) * 16];
#pragma unroll
    for (int n = 0; n < 16; n += 4)
        *(float4*)&hp[n] = make_float4(h[n], h[n + 1], h[n + 2], h[n + 3]);
    Ssum[((size_t)b * NC + c) * D_INNER + d] = S;
}

// ---------------------------------------------------------------------------
// K5b: combine chunks serially (in place: hloc becomes h_init per chunk).
__global__ __launch_bounds__(256) void scan_phase2(const float* __restrict__ A, const float* __restrict__ Ssum,
                                                   float* __restrict__ hloc) {
    int tid = blockIdx.x * 256 + threadIdx.x;
    int n = tid & 15;
    int d = (tid >> 4) & (D_INNER - 1);
    int b = tid >> 16;
    float An = A[d * 16 + n];
    float h = 0.f;
    for (int c = 0; c < NC; c++) {
        size_t idx = (((size_t)b * NC + c) * D_INNER + d) * 16 + n;
        float hl = hloc[idx];
        float S = Ssum[((size_t)b * NC + c) * D_INNER + d];
        hloc[idx] = h;
        h = hl + h * __expf(An * S);
    }
}

// ---------------------------------------------------------------------------
// K5c: phase 3 — rerun chunk with h_init, compute y, D-residual, silu(z) gate.
__global__ __launch_bounds__(256) void scan_phase3(const float* __restrict__ proj, const u16* __restrict__ dt,
                                                   const float* __restrict__ A, const u16* __restrict__ D16,
                                                   const float* __restrict__ hinit, const u16* __restrict__ z16,
                                                   u16* __restrict__ xs) {
    __shared__ float BC[TC][32];
    int d = blockIdx.x * 256 + threadIdx.x;
    int c = blockIdx.y, b = blockIdx.z;
    int t0 = c * TC;
    {
        int i = threadIdx.x >> 2;
        int q = threadIdx.x & 3;
        const float* src = proj + ((size_t)b * SEQLEN + t0 + i) * PST + DT_RANK + q * 8;
        *(float4*)&BC[i][q * 8 + 0] = *(const float4*)(src + 0);
        *(float4*)&BC[i][q * 8 + 4] = *(const float4*)(src + 4);
    }
    __syncthreads();
    float Areg[16];
#pragma unroll
    for (int n = 0; n < 16; n++) Areg[n] = A[d * 16 + n];
    float h[16];
    {
        const float* hp = &hinit[(((size_t)b * NC + c) * D_INNER + d) * 16];
#pragma unroll
        for (int n = 0; n < 16; n += 4) {
            float4 v = *(const float4*)&hp[n];
            h[n] = v.x; h[n + 1] = v.y; h[n + 2] = v.z; h[n + 3] = v.w;
        }
    }
    float Dd = bf2f(D16[d]);
    size_t base = ((size_t)b * SEQLEN + t0) * D_INNER + d;
    for (int t = 0; t < TC; t++) {
        size_t idx = base + (size_t)t * D_INNER;
        float dtv = bf2f(dt[idx]);
        float u = bf2f(xs[idx]);
        float zv = bf2f(z16[idx]);
        float du = dtv * u;
        float y = 0.f;
#pragma unroll
        for (int n = 0; n < 16; n++) {
            h[n] = h[n] * __expf(dtv * Areg[n]) + du * BC[t][n];
            y += h[n] * BC[t][16 + n];
        }
        float gate = zv / (1.f + __expf(-zv));
        xs[idx] = f2bf((y + u * Dd) * gate);
    }
}

// ---------------------------------------------------------------------------
extern "C" void kernel_launch(void* const* d_in, const int* in_sizes, int n_in,
                              void* d_out, int out_size, void* d_ws, size_t ws_size,
                              hipStream_t stream) {
    const void* x          = d_in[0];
    const void* in_proj_w  = d_in[1];
    const void* conv_w     = d_in[2];
    const void* conv_b     = d_in[3];
    const void* x_proj_w   = d_in[4];
    const void* dt_proj_w  = d_in[5];
    const void* dt_proj_b  = d_in[6];
    const void* A_log      = d_in[7];
    const void* Dvec       = d_in[8];
    const void* out_proj_w = d_in[9];

    char* w = (char*)d_ws;
    const size_t MB = 1024 * 1024;
    int*   flag  = (int*)(w + 0);
    float* Aws   = (float*)(w + 1024);
    float* proj  = (float*)(w + 1 * MB);   // 2 MB fp32 [4096][PST=128]
    u16*   cw16  = (u16*)(w + 3 * MB);
    u16*   cb16  = (u16*)(w + 3 * MB + 64 * 1024);
    u16*   dtw16 = (u16*)(w + 4 * MB);
    u16*   dtb16 = (u16*)(w + 4 * MB + 600 * 1024);
    u16*   D16   = (u16*)(w + 4 * MB + 700 * 1024);
    u16*   buf1  = (u16*)(w + 5 * MB);     // 32 MB: xc then z
    u16*   xs    = (u16*)(w + 37 * MB);    // 32 MB: xs then gated y
    u16*   dt16  = (u16*)(w + 69 * MB);    // 32 MB (overlays x16/ipwT after they die)
    u16*   x16   = (u16*)(w + 69 * MB);    // 8.4 MB
    u16*   ipwT  = (u16*)(w + 78 * MB);    // 16.8 MB: in_proj_w^T [8192][1024]
    float* hloc  = (float*)(w + 101 * MB); // 16 MB
    float* Ssum  = (float*)(w + 117 * MB); // 1 MB
    u16*   opwT  = (u16*)(w + 118 * MB);   // 8.4 MB: out_proj_w^T [1024][4096]
    u16*   xpwT  = (u16*)(w + 127 * MB);   // 1 MB: x_proj_w^T [96(pad128)][4096]
    float* Pp    = (float*)(w + 128 * MB); // 16 MB: split-K partials [8][4096][128]
    // total 144 MB (<150 MB proven available)

    detect_dtype<<<dim3(1), dim3(256), 0, stream>>>((const u16*)x, flag);
    ingest16<<<dim3(64), dim3(256), 0, stream>>>(conv_w, cw16, D_INNER * D_CONV, flag);
    ingest16<<<dim3(16), dim3(256), 0, stream>>>(conv_b, cb16, D_INNER, flag);
    ingest16<<<dim3(1024), dim3(256), 0, stream>>>(dt_proj_w, dtw16, DT_RANK * D_INNER, flag);
    ingest16<<<dim3(16), dim3(256), 0, stream>>>(dt_proj_b, dtb16, D_INNER, flag);
    ingest16<<<dim3(16), dim3(256), 0, stream>>>(Dvec, D16, D_INNER, flag);
    prep_A<<<dim3(256), dim3(256), 0, stream>>>(A_log, Aws, flag);
    ingest16<<<dim3(MROWS * D_MODEL / 256), dim3(256), 0, stream>>>(x, x16, MROWS * D_MODEL, flag);
    transpose_w<<<dim3(2 * D_INNER / 32, D_MODEL / 32), dim3(256), 0, stream>>>(in_proj_w, ipwT, D_MODEL, 2 * D_INNER, flag);
    transpose_w<<<dim3(D_MODEL / 32, D_INNER / 32), dim3(256), 0, stream>>>(out_proj_w, opwT, D_INNER, D_MODEL, flag);
    transpose_w<<<dim3(NPROJ / 32, D_INNER / 32), dim3(256), 0, stream>>>(x_proj_w, xpwT, D_INNER, NPROJ, flag);

    // K1a: xc = x @ Win[:, :4096]
    gemm_bt<<<dim3(D_INNER / 128, MROWS / 128), dim3(256), 0, stream>>>(
        x16, ipwT, D_MODEL, buf1, D_INNER, 0, flag);
    // K2: conv + silu -> xs
    conv_silu<<<dim3(MROWS * D_INNER / 256), dim3(256), 0, stream>>>(buf1, cw16, cb16, xs);
    // K1b: z = x @ Win[:, 4096:]  (overwrites xc, dead after conv)
    gemm_bt<<<dim3(D_INNER / 128, MROWS / 128), dim3(256), 0, stream>>>(
        x16, ipwT + (size_t)D_INNER * D_MODEL, D_MODEL, buf1, D_INNER, 0, flag);
    // K3: proj via split-K MFMA + reduce
    gemm_proj<<<dim3(KSPLIT, MROWS / 128), dim3(256), 0, stream>>>(xs, xpwT, Pp);
    reduce_proj<<<dim3(MROWS * PST / 256), dim3(256), 0, stream>>>(Pp, proj);
    // K4: dt bf16 (overwrites x16/ipwT region - both dead)
    dt_gemm<<<dim3(D_INNER / 256, MROWS / 16), dim3(256), 0, stream>>>(proj, dtw16, dtb16, dt16);
    // K5: chunked scan
    scan_phase1<<<dim3(D_INNER / 256, NC, BATCH), dim3(256), 0, stream>>>(proj, dt16, Aws, xs, hloc, Ssum);
    scan_phase2<<<dim3(BATCH * D_INNER * D_STATE / 256), dim3(256), 0, stream>>>(Aws, Ssum, hloc);
    scan_phase3<<<dim3(D_INNER / 256, NC, BATCH), dim3(256), 0, stream>>>(proj, dt16, Aws, D16, hloc, buf1, xs);
    // K6: out = y @ out_proj_w
    gemm_bt<<<dim3(D_MODEL / 128, MROWS / 128), dim3(256), 0, stream>>>(
        xs, opwT, D_INNER, d_out, D_MODEL, 1, flag);
}